// Round 14
// baseline (165.189 us; speedup 1.0000x reference)
//
#include <hip/hip_runtime.h>
#include <hip/hip_bf16.h>

// ---------------- problem constants ----------------
#define HOP    1024
#define NFREQ  2049
#define NTIME  431
#define SIGLEN 441000
#define N_REAL 3448            // 8*431
#define MH     1025            // k rows per half-product (0..1024)
#define KH     1088            // folded half-K: 1025 -> pad to 17*64
#define KH32   34              // KH/32 fragment columns
#define NT2    17              // K-tiles per bank
#define M_PADH 1152            // 9*128
#define MBLK2  9
#define N_PAD2 3456            // 27*128
#define NBLK2  27
#define NPAIR2 (MBLK2 * NBLK2) // 243 (bm,bn) pairs per product
#define MGRP   136             // KH/8

typedef unsigned short ushort_t;
typedef unsigned int   uint_t;
typedef __attribute__((ext_vector_type(8))) __bf16 bf16x8;
typedef __attribute__((ext_vector_type(4))) float  f32x4;
typedef const __attribute__((address_space(1))) bf16x8* gcv_t;

// float -> bf16 (round-to-nearest-even)
__device__ __forceinline__ ushort_t f2bf(float f) {
    uint_t u = __builtin_bit_cast(uint_t, f);
    u = (u + 0x7FFFu + ((u >> 16) & 1u)) >> 16;
    return (ushort_t)u;
}

__device__ __forceinline__ float frame_sample(const float* __restrict__ xs, int pos) {
    if (pos < 0) pos = -pos;
    else if (pos >= SIGLEN) pos = 2 * SIGLEN - 2 - pos;
    return xs[pos];
}

// filter value, generated by trig (matches provided buffers: window*norm, sin negated)
__device__ __forceinline__ float filt_val(int g, int k, int n) {
    float r = (float)(k * n) * (1.0f / 4096.0f);
    r -= floorf(r);
    const float w = 0.5f - 0.5f * cospif((float)n * (1.0f / 2048.0f));
    const float t = g ? -sinpif(2.0f * r) : cospif(2.0f * r);
    return t * w * 0.015625f;
}

// ---------------- fused prep ----------------
// A[g][par][k][m] row-major (staged to LDS with swizzled source, as before).
// B[g][par] FRAGMENT-MAJOR: frag (n16, k32) = 64 lanes x 8 bf16; lane l holds
// B[n16*16 + (l&15)][k32*32 + (l>>4)*8 .. +7]. GEMM loads it as one coalesced
// 1KB global_load_dwordx4 per fragment (no LDS for B).
__global__ __launch_bounds__(256) void build_prep(
        const float* __restrict__ x,
        ushort_t* __restrict__ Aall, ushort_t* __restrict__ Ball) {
    const long TA = 2L * M_PADH * MGRP;
    const long TB = (long)N_PAD2 * MGRP;
    const long stride = (long)gridDim.x * blockDim.x;
    for (long task = (long)blockIdx.x * blockDim.x + threadIdx.x; task < TA + TB; task += stride) {
        if (task < TA) {
            const int g  = (int)(task / (M_PADH * MGRP));
            const int r  = (int)(task - (long)g * (M_PADH * MGRP));
            const int k  = r / MGRP;
            const int mg = r - k * MGRP;
            const int m0 = mg * 8;
            alignas(16) ushort_t ve[8], vo[8];
            #pragma unroll
            for (int j = 0; j < 8; ++j) { ve[j] = 0; vo[j] = 0; }
            if (k < MH) {
                #pragma unroll
                for (int j = 0; j < 8; ++j) {
                    const int m = m0 + j;
                    if (m <= 1024) ve[j] = f2bf(filt_val(g, k, 2 * m));
                    if (m <= 1023) vo[j] = f2bf(filt_val(g, k, 2 * m + 1));
                }
            }
            const long dst = ((long)(g * 2) * M_PADH + k) * KH + m0;
            *reinterpret_cast<uint4*>(Aall + dst) = *reinterpret_cast<const uint4*>(ve);
            *reinterpret_cast<uint4*>(Aall + dst + (long)M_PADH * KH) = *reinterpret_cast<const uint4*>(vo);
        } else {
            const long r = task - TA;
            const int n  = (int)(r / MGRP);
            const int mg = (int)(r - (long)n * MGRP);
            const int m0 = mg * 8;
            alignas(16) ushort_t ee[8], eo[8], oe[8], oo[8];
            #pragma unroll
            for (int j = 0; j < 8; ++j) { ee[j] = 0; eo[j] = 0; oe[j] = 0; oo[j] = 0; }
            if (n < N_REAL) {
                const int s = n / NTIME;
                const int t = n - s * NTIME;
                const float* xs = x + (long)s * SIGLEN;
                const int base = t * HOP - 2048;
                const bool interior = (t >= 2) && (t <= 428);
                if (interior && mg <= 127) {
                    const float* fp = xs + base + 2 * m0;
                    const float4 f0 = ((const float4*)fp)[0];
                    const float4 f1 = ((const float4*)fp)[1];
                    const float4 f2 = ((const float4*)fp)[2];
                    const float4 f3 = ((const float4*)fp)[3];
                    const float fe[8] = {f0.x,f0.z,f1.x,f1.z,f2.x,f2.z,f3.x,f3.z};
                    const float fo[8] = {f0.y,f0.w,f1.y,f1.w,f2.y,f2.w,f3.y,f3.w};
                    const float* gp = xs + base + 4096 - 2 * m0 - 16;
                    const float4 h0 = ((const float4*)gp)[0];
                    const float4 h1 = ((const float4*)gp)[1];
                    const float4 h2 = ((const float4*)gp)[2];
                    const float4 h3 = ((const float4*)gp)[3];
                    const float h16 = gp[16];
                    const float hh[17] = {h0.x,h0.y,h0.z,h0.w, h1.x,h1.y,h1.z,h1.w,
                                          h2.x,h2.y,h2.z,h2.w, h3.x,h3.y,h3.z,h3.w, h16};
                    #pragma unroll
                    for (int j = 0; j < 8; ++j) {
                        const float me = hh[16 - 2 * j];
                        const float mo = hh[15 - 2 * j];
                        ee[j] = f2bf(fe[j] + me);
                        oe[j] = f2bf(fe[j] - me);
                        eo[j] = f2bf(fo[j] + mo);
                        oo[j] = f2bf(fo[j] - mo);
                    }
                    if (mg == 0) {   // m=0: ide=0 has no mirror term
                        ee[0] = f2bf(fe[0]);
                        oe[0] = f2bf(fe[0]);
                    }
                } else if (mg <= 128) {
                    #pragma unroll
                    for (int j = 0; j < 8; ++j) {
                        const int m = m0 + j;
                        const int ide = 2 * m;
                        if (m <= 1024) {
                            const float fn = frame_sample(xs, base + ide);
                            const float fm = (ide >= 1 && ide <= 2047) ? frame_sample(xs, base + 4096 - ide) : 0.0f;
                            ee[j] = f2bf(fn + fm);
                            oe[j] = f2bf(fn - fm);
                        }
                        if (m <= 1023) {
                            const int ido = 2 * m + 1;
                            const float gn = frame_sample(xs, base + ido);
                            const float gm = frame_sample(xs, base + 4096 - ido);
                            eo[j] = f2bf(gn + gm);
                            oo[j] = f2bf(gn - gm);
                        }
                    }
                }
            }
            const long MSZ = (long)N_PAD2 * KH;
            // fragment-major offset: frag (n>>4, m0>>5), lane ((m0>>3)&3)<<4 | (n&15)
            const long foff = ((long)(n >> 4) * KH32 + (m0 >> 5)) * 512
                            + (long)(((((m0 >> 3) & 3) << 4) | (n & 15)) * 8);
            *reinterpret_cast<uint4*>(Ball + foff)           = *reinterpret_cast<const uint4*>(ee);
            *reinterpret_cast<uint4*>(Ball + foff + MSZ)     = *reinterpret_cast<const uint4*>(eo);
            *reinterpret_cast<uint4*>(Ball + foff + 2 * MSZ) = *reinterpret_cast<const uint4*>(oe);
            *reinterpret_cast<uint4*>(Ball + foff + 3 * MSZ) = *reinterpret_cast<const uint4*>(oo);
        }
    }
}

// ---------------- async global -> LDS ----------------
__device__ __forceinline__ void gload_lds16(const ushort_t* g, ushort_t* l) {
    __builtin_amdgcn_global_load_lds(
        (const __attribute__((address_space(1))) void*)g,
        (__attribute__((address_space(3))) void*)l,
        16, 0, 0);
}

__device__ __forceinline__ f32x4 MF(bf16x8 x, bf16x8 y, f32x4 c) {
    return __builtin_amdgcn_mfma_f32_16x16x32_bf16(x, y, c, 0, 0, 0);
}

#define SBAR()  __builtin_amdgcn_s_barrier()
#define SCHED() __builtin_amdgcn_sched_barrier(0)

// ---------------- 128x128 banks-in-waves bf16 GEMM ----------------
// 512 threads = 8 waves: wave wv -> bank par=wv&1 (even/odd samples), quadrant
// q=wv>>1 (wm=q&1, wn=q>>1), 64x64 wave tile, SINGLE-bank acc (64 regs).
// A in LDS (16KB/bank/buf, dbuf, swizzled source); B read directly from global
// in fragment-major layout (8 coalesced 1KB loads/wave/tile, L1/L2-hot).
// 17 K-iterations, ONE barrier each:
//   {8 b-loads | 8 a-ds_reads | 32 MFMA} lgkm(0) vmcnt(0) SBAR {stage A(t+2): 4}
// vmcnt(0)/lgkm(0) are ~1 iteration stale -> free. Epilogue: E-waves dump acc
// to LDS (stride-68 pad), O-waves combine (radix-2) and store.
// 2 blocks/CU (64KB LDS) x 8 waves = 16 waves/CU. XCD-locality decode as R11.
__global__ __launch_bounds__(512, 4) void stft_gemm(
        const ushort_t* __restrict__ Aall, const ushort_t* __restrict__ Ball,
        float* __restrict__ out) {
    __shared__ alignas(16) ushort_t LDSBUF[4 * 8192];   // [par][buf][128*64] = 64KB

    const int pid = blockIdx.x;
    const int xc  = pid & 7;           // XCD home (round-robin, m09)
    const int g   = (pid >> 3) & 1;    // 0: cos->real, 1: sin->imag
    const int i   = pid >> 4;          // index within XCD chunk
    const int sz  = (xc < 3) ? 31 : 30;
    if (i >= sz) return;
    const int p   = xc * 30 + ((xc < 3) ? xc : 3) + i;   // bn-major pair index
    const int bm  = p % MBLK2;
    const int bn  = p / MBLK2;

    const int tid  = threadIdx.x;
    const int lane = tid & 63;
    const int wv   = tid >> 6;
    const int par  = wv & 1;           // 0: even-sample bank, 1: odd
    const int q    = wv >> 1;
    const int wm   = q & 1;
    const int wn   = q >> 1;

    const ushort_t* A0 = Aall + (long)(g * 2) * M_PADH * KH;       // even bank A
    const ushort_t* A1 = A0 + (long)M_PADH * KH;                   // odd bank A
    const ushort_t* Bmat = Ball + (long)(g * 2 + par) * N_PAD2 * KH; // my bank's B'

    const long Ar0 = (long)bm * 128;

    // A staging: one issue = 64 rows x 128B (512 threads x 16B), LINEAR LDS dest,
    // XOR swizzle applied to the GLOBAL source column.
    const int rb   = tid >> 3;                                      // 0..63
    const int scol = ((((tid & 7) << 4) ^ ((rb & 7) << 4)) >> 1);   // src-swizzled col
    const int ldsw = wv * 512;                                      // wave slice of issue

    auto STG1 = [&](const ushort_t* G, long row0, int kc, ushort_t* dst8k) {
        const ushort_t* gp = G + (row0 + rb) * (long)KH + kc + scol;
        gload_lds16(gp, dst8k + ldsw);
    };
    // stage both banks' A tile t into buf slot
    auto STAGE = [&](int t, int buf) {
        const int kc = t * 64;
        ushort_t* de = LDSBUF + buf * 8192;            // par0: [buf][8192]
        ushort_t* do_ = LDSBUF + (2 + buf) * 8192;     // par1
        STG1(A0, Ar0,      kc, de);
        STG1(A0, Ar0 + 64, kc, de + 4096);
        STG1(A1, Ar0,      kc, do_);
        STG1(A1, Ar0 + 64, kc, do_ + 4096);
    };

    const int lrow = lane & 15;
    const int kq   = (lane >> 4) << 4;
    auto FRAG = [&](const ushort_t* buf, int lr, int kb) -> bf16x8 {
        const char* pp = reinterpret_cast<const char*>(buf)
                        + lr * 128 + ((kb + kq) ^ ((lr & 7) << 4));
        return *reinterpret_cast<const bf16x8*>(pp);
    };

    f32x4 acc[4][4] = {};
    bf16x8 a[4][2], b[4][2];
    const int arow = wm * 64 + lrow;
    const ushort_t* AsP = LDSBUF + par * 2 * 8192;     // my bank's A buffers
    const long n16b = (long)(bn * 8 + wn * 4);         // my first b-frag row-block

    // ---- prologue: tiles 0,1 for both banks (8 issues/wave) ----
    STAGE(0, 0);
    STAGE(1, 1);
    asm volatile("s_waitcnt vmcnt(4)" ::: "memory");   // tile0's 4 retired (in-order)
    SBAR();

    for (int t = 0; t < NT2; ++t) {
        const int cur = t & 1;
        const ushort_t* Ac = AsP + cur * 8192;

        // 8 coalesced b-frag loads from global (frag-major) + 8 a ds_reads
        {
            const long f0 = (n16b * KH32 + t * 2) << 9;
            #pragma unroll
            for (int nf = 0; nf < 4; ++nf) {
                const ushort_t* bp = Bmat + f0 + (((long)nf * KH32) << 9) + (lane << 3);
                b[nf][0] = *(gcv_t)bp;
                b[nf][1] = *(gcv_t)(bp + 512);
            }
        }
        #pragma unroll
        for (int mf = 0; mf < 4; ++mf) {
            a[mf][0] = FRAG(Ac, arow + mf * 16, 0);
            a[mf][1] = FRAG(Ac, arow + mf * 16, 64);
        }
        __builtin_amdgcn_s_setprio(1);
        #pragma unroll
        for (int mf = 0; mf < 4; ++mf)
            #pragma unroll
            for (int nf = 0; nf < 4; ++nf) {
                acc[mf][nf] = MF(a[mf][0], b[nf][0], acc[mf][nf]);
                acc[mf][nf] = MF(a[mf][1], b[nf][1], acc[mf][nf]);
            }
        __builtin_amdgcn_s_setprio(0);
        // my a-reads delivered; stage(t+1) (issued last iter) drained -> barrier
        asm volatile("s_waitcnt lgkmcnt(0)" ::: "memory");
        asm volatile("s_waitcnt vmcnt(0)" ::: "memory");
        SCHED();
        SBAR();
        if (t + 2 < NT2) STAGE(t + 2, cur);   // overwrite cur: all reads done
    }

    // ---- epilogue: E-waves dump acc to LDS; O-waves combine + store ----
    // region per quadrant: [32 n][64 m] floats, stride 68 (2-way conflicts only)
    float* fb   = reinterpret_cast<float*>(LDSBUF);
    float* qbuf = fb + q * 2176;
    const int row_off = (lane >> 4) << 2;
    const int col_off = lane & 15;
    const int kg  = bm * 128 + wm * 64;
    const int ng0 = bn * 128 + wn * 64;

    SBAR();   // all K-loop LDS traffic complete before reuse as float buffer
    #pragma unroll
    for (int rr = 0; rr < 2; ++rr) {
        if (par == 0) {
            #pragma unroll
            for (int nfr = 0; nfr < 2; ++nfr)
                #pragma unroll
                for (int mf = 0; mf < 4; ++mf)
                    *reinterpret_cast<f32x4*>(&qbuf[(nfr * 16 + col_off) * 68 + mf * 16 + row_off])
                        = acc[mf][rr * 2 + nfr];
        }
        SBAR();
        if (par == 1) {
            #pragma unroll
            for (int nfr = 0; nfr < 2; ++nfr) {
                const int nf = rr * 2 + nfr;
                const int ng = ng0 + nf * 16 + col_off;
                if (ng < N_REAL) {
                    const int s  = ng / NTIME;
                    const int tt = ng - s * NTIME;
                    const long rowbase = (long)s * NFREQ * NTIME;
                    #pragma unroll
                    for (int mf = 0; mf < 4; ++mf) {
                        const f32x4 e = *reinterpret_cast<const f32x4*>(
                            &qbuf[(nfr * 16 + col_off) * 68 + mf * 16 + row_off]);
                        #pragma unroll
                        for (int r4 = 0; r4 < 4; ++r4) {
                            const int k = kg + mf * 16 + row_off + r4;
                            if (k < MH) {
                                const float vE = e[r4];
                                const float vO = acc[mf][nf][r4];
                                const float vP = vE + vO;
                                const float vM = g ? (vO - vE) : (vE - vO);
                                out[(rowbase + (long)k * NTIME + tt) * 2 + g]          = vP;
                                out[(rowbase + (long)(2048 - k) * NTIME + tt) * 2 + g] = vM;
                            }
                        }
                    }
                }
            }
        }
        SBAR();
    }
}

extern "C" void kernel_launch(void* const* d_in, const int* in_sizes, int n_in,
                              void* d_out, int out_size, void* d_ws, size_t ws_size,
                              hipStream_t stream) {
    const float* x    = (const float*)d_in[0];
    float* out = (float*)d_out;

    ushort_t* Aall = (ushort_t*)d_ws;                     // 4 * 1152*1088*2B = 10.0MB
    ushort_t* Ball = Aall + 4L * M_PADH * KH;             // 4 * 3456*1088*2B = 30.1MB

    build_prep<<<2048, 256, 0, stream>>>(x, Aall, Ball);

    // 486 active blocks; pid encodes (chunk-index, g, XCD); grid padded to 496
    stft_gemm<<<496, 512, 0, stream>>>(Aall, Ball, out);
}

// Round 15
// 74.913 us; speedup vs baseline: 2.2051x; 2.2051x over previous
//
#include <hip/hip_runtime.h>
#include <hip/hip_bf16.h>

// ---------------- problem constants ----------------
#define HOP    1024
#define NFREQ  2049
#define NTIME  431
#define SIGLEN 441000
#define N_REAL 3448            // 8*431
#define MH     1025            // k rows per half-product (0..1024)
#define KH     1088            // folded half-K: 1025 -> pad to 17*64
#define NT2    17              // K-tiles per sub-GEMM
#define NTT    34              // total K-tiles per block (even + odd)
#define M_PADH 1152            // 9*128
#define MBLK2  9
#define N_PAD2 3456            // 27*128
#define NBLK2  27
#define NPAIR2 (MBLK2 * NBLK2) // 243 (bm,bn) pairs per product
#define MGRP   136             // KH/8

typedef unsigned short ushort_t;
typedef unsigned int   uint_t;
typedef __attribute__((ext_vector_type(8))) __bf16 bf16x8;
typedef __attribute__((ext_vector_type(4))) float  f32x4;

// float -> bf16 (round-to-nearest-even)
__device__ __forceinline__ ushort_t f2bf(float f) {
    uint_t u = __builtin_bit_cast(uint_t, f);
    u = (u + 0x7FFFu + ((u >> 16) & 1u)) >> 16;
    return (ushort_t)u;
}

__device__ __forceinline__ float frame_sample(const float* __restrict__ xs, int pos) {
    if (pos < 0) pos = -pos;
    else if (pos >= SIGLEN) pos = 2 * SIGLEN - 2 - pos;
    return xs[pos];
}

// filter value, generated by trig (matches provided buffers: window*norm, sin negated)
// k*n <= 1024*2049 < 2^24 -> exact in fp32; /4096 exact; fract exact.
__device__ __forceinline__ float filt_val(int g, int k, int n) {
    float r = (float)(k * n) * (1.0f / 4096.0f);
    r -= floorf(r);                                   // revolutions in [0,1)
    const float w = 0.5f - 0.5f * cospif((float)n * (1.0f / 2048.0f));
    const float t = g ? -sinpif(2.0f * r) : cospif(2.0f * r);
    return t * w * 0.015625f;                         // norm = 1/sqrt(4096)
}

// ---------------- fused prep ----------------
// A[g][par][k][m] = filt_g(k, 2m+par): trig-generated (no filter reads).
// B[g][par][n][m]: g0 uses E=fn+fm, g1 uses O=fn-fm; par0 idx=2m, par1 idx=2m+1.
__global__ __launch_bounds__(256) void build_prep(
        const float* __restrict__ x,
        ushort_t* __restrict__ Aall, ushort_t* __restrict__ Ball) {
    const long TA = 2L * M_PADH * MGRP;
    const long TB = (long)N_PAD2 * MGRP;
    const long stride = (long)gridDim.x * blockDim.x;
    for (long task = (long)blockIdx.x * blockDim.x + threadIdx.x; task < TA + TB; task += stride) {
        if (task < TA) {
            const int g  = (int)(task / (M_PADH * MGRP));
            const int r  = (int)(task - (long)g * (M_PADH * MGRP));
            const int k  = r / MGRP;
            const int mg = r - k * MGRP;
            const int m0 = mg * 8;
            alignas(16) ushort_t ve[8], vo[8];
            #pragma unroll
            for (int j = 0; j < 8; ++j) { ve[j] = 0; vo[j] = 0; }
            if (k < MH) {
                #pragma unroll
                for (int j = 0; j < 8; ++j) {
                    const int m = m0 + j;
                    if (m <= 1024) ve[j] = f2bf(filt_val(g, k, 2 * m));
                    if (m <= 1023) vo[j] = f2bf(filt_val(g, k, 2 * m + 1));
                }
            }
            const long dst = ((long)(g * 2) * M_PADH + k) * KH + m0;
            *reinterpret_cast<uint4*>(Aall + dst) = *reinterpret_cast<const uint4*>(ve);
            *reinterpret_cast<uint4*>(Aall + dst + (long)M_PADH * KH) = *reinterpret_cast<const uint4*>(vo);
        } else {
            const long r = task - TA;
            const int n  = (int)(r / MGRP);
            const int mg = (int)(r - (long)n * MGRP);
            const int m0 = mg * 8;
            alignas(16) ushort_t ee[8], eo[8], oe[8], oo[8];
            #pragma unroll
            for (int j = 0; j < 8; ++j) { ee[j] = 0; eo[j] = 0; oe[j] = 0; oo[j] = 0; }
            if (n < N_REAL) {
                const int s = n / NTIME;
                const int t = n - s * NTIME;
                const float* xs = x + (long)s * SIGLEN;
                const int base = t * HOP - 2048;
                const bool interior = (t >= 2) && (t <= 428);
                if (interior && mg <= 127) {
                    const float* fp = xs + base + 2 * m0;
                    const float4 f0 = ((const float4*)fp)[0];
                    const float4 f1 = ((const float4*)fp)[1];
                    const float4 f2 = ((const float4*)fp)[2];
                    const float4 f3 = ((const float4*)fp)[3];
                    const float fe[8] = {f0.x,f0.z,f1.x,f1.z,f2.x,f2.z,f3.x,f3.z};
                    const float fo[8] = {f0.y,f0.w,f1.y,f1.w,f2.y,f2.w,f3.y,f3.w};
                    const float* gp = xs + base + 4096 - 2 * m0 - 16;
                    const float4 h0 = ((const float4*)gp)[0];
                    const float4 h1 = ((const float4*)gp)[1];
                    const float4 h2 = ((const float4*)gp)[2];
                    const float4 h3 = ((const float4*)gp)[3];
                    const float h16 = gp[16];
                    const float hh[17] = {h0.x,h0.y,h0.z,h0.w, h1.x,h1.y,h1.z,h1.w,
                                          h2.x,h2.y,h2.z,h2.w, h3.x,h3.y,h3.z,h3.w, h16};
                    #pragma unroll
                    for (int j = 0; j < 8; ++j) {
                        const float me = hh[16 - 2 * j];
                        const float mo = hh[15 - 2 * j];
                        ee[j] = f2bf(fe[j] + me);
                        oe[j] = f2bf(fe[j] - me);
                        eo[j] = f2bf(fo[j] + mo);
                        oo[j] = f2bf(fo[j] - mo);
                    }
                    if (mg == 0) {   // m=0: ide=0 has no mirror term
                        ee[0] = f2bf(fe[0]);
                        oe[0] = f2bf(fe[0]);
                    }
                } else if (mg <= 128) {
                    #pragma unroll
                    for (int j = 0; j < 8; ++j) {
                        const int m = m0 + j;
                        const int ide = 2 * m;
                        if (m <= 1024) {
                            const float fn = frame_sample(xs, base + ide);
                            const float fm = (ide >= 1 && ide <= 2047) ? frame_sample(xs, base + 4096 - ide) : 0.0f;
                            ee[j] = f2bf(fn + fm);
                            oe[j] = f2bf(fn - fm);
                        }
                        if (m <= 1023) {
                            const int ido = 2 * m + 1;
                            const float gn = frame_sample(xs, base + ido);
                            const float gm = frame_sample(xs, base + 4096 - ido);
                            eo[j] = f2bf(gn + gm);
                            oo[j] = f2bf(gn - gm);
                        }
                    }
                }
            }
            const long MSZ = (long)N_PAD2 * KH;
            const long dst = (long)n * KH + m0;
            *reinterpret_cast<uint4*>(Ball + dst)           = *reinterpret_cast<const uint4*>(ee);
            *reinterpret_cast<uint4*>(Ball + dst + MSZ)     = *reinterpret_cast<const uint4*>(eo);
            *reinterpret_cast<uint4*>(Ball + dst + 2 * MSZ) = *reinterpret_cast<const uint4*>(oe);
            *reinterpret_cast<uint4*>(Ball + dst + 3 * MSZ) = *reinterpret_cast<const uint4*>(oo);
        }
    }
}

// ---------------- async global -> LDS ----------------
__device__ __forceinline__ void gload_lds16(const ushort_t* g, ushort_t* l) {
    __builtin_amdgcn_global_load_lds(
        (const __attribute__((address_space(1))) void*)g,
        (__attribute__((address_space(3))) void*)l,
        16, 0, 0);
}

__device__ __forceinline__ f32x4 MF(bf16x8 x, bf16x8 y, f32x4 c) {
    return __builtin_amdgcn_mfma_f32_16x16x32_bf16(x, y, c, 0, 0, 0);
}

#define SBAR()  __builtin_amdgcn_s_barrier()
#define SCHED() __builtin_amdgcn_sched_barrier(0)

// ---------------- 128x128 dual-bank bf16 GEMM, B triple-buffered ----------------
// R11 structure (256 thr, 4 waves 2Mx2N, XCD-locality decode, twin write pairing)
// with ONE change: Bs has 3 buffers (LDS 80KB, still exactly 2 blocks/CU) and
// B(t+2) is staged at the TOP of iter t into Bs[(t+2)%3] — that buffer's readers
// finished at iter t-1's mid lgkm(0)+barrier, so the write is WAR-safe, and the
// B staging latency overlaps a full compute phase instead of sitting between the
// two barriers. A stays double-buffered (staged after the mid barrier as in R11).
// End-of-iter vmcnt(8) leaves exactly [B(t+2):4][A(t+2):4] outstanding ->
// tile t+1 (A and B) proven landed by in-order retirement.
__global__ __launch_bounds__(256, 2) void stft_gemm(
        const ushort_t* __restrict__ Aall, const ushort_t* __restrict__ Ball,
        float* __restrict__ out) {
    __shared__ alignas(16) ushort_t As[2][128 * 64];
    __shared__ alignas(16) ushort_t Bs[3][128 * 64];

    const int pid = blockIdx.x;
    const int xc  = pid & 7;           // XCD home (round-robin, m09)
    const int g   = (pid >> 3) & 1;    // 0: cos->real, 1: sin->imag
    const int i   = pid >> 4;          // index within XCD chunk
    const int sz  = (xc < 3) ? 31 : 30;
    if (i >= sz) return;
    const int p   = xc * 30 + ((xc < 3) ? xc : 3) + i;   // bn-major pair index
    const int bm  = p % MBLK2;
    const int bn  = p / MBLK2;

    const int tid  = threadIdx.x;
    const int lane = tid & 63;
    const int wv   = tid >> 6;
    const int wm   = wv & 1;
    const int wn   = wv >> 1;

    const ushort_t* A0 = Aall + (long)(g * 2) * M_PADH * KH;   // even-sample filters
    const ushort_t* A1 = A0 + (long)M_PADH * KH;               // odd
    const ushort_t* B0 = Ball + (long)(g * 2) * N_PAD2 * KH;   // even-sample frames
    const ushort_t* B1 = B0 + (long)N_PAD2 * KH;               // odd

    const long Ar0 = (long)bm * 128;
    const long Br0 = (long)bn * 128;

    const int rb   = tid >> 3;                                      // 0..31
    const int scol = ((((tid & 7) << 4) ^ ((rb & 7) << 4)) >> 1);   // src-swizzled ushort col
    const int ldsw = wv * 512;                                      // wave-uniform LDS base

    auto STG = [&](const ushort_t* Gb, long r0, int kcol, ushort_t* dst, int half) {
        const ushort_t* gp = Gb + (r0 + half * 64 + rb) * (long)KH + kcol + scol;
        gload_lds16(gp,                 dst + half * 4096 + ldsw);
        gload_lds16(gp + 32 * (long)KH, dst + half * 4096 + 2048 + ldsw);
    };

    const int lrow = lane & 15;
    const int kq   = (lane >> 4) << 4;
    auto FRAG = [&](const ushort_t* buf, int lr, int kb) -> bf16x8 {
        const char* pp = reinterpret_cast<const char*>(buf)
                        + lr * 128 + ((kb + kq) ^ ((lr & 7) << 4));
        return *reinterpret_cast<const bf16x8*>(pp);
    };

    f32x4 accE[4][4] = {}, accO[4][4] = {};
    bf16x8 a[4][2], b[4][2];
    const int arow = wm * 64 + lrow;
    const int brow = wn * 64 + lrow;

    auto ABK = [&](int j, const ushort_t*& Ab, const ushort_t*& Bb, int& kc) {
        if (j >= NT2) { Ab = A1; Bb = B1; kc = (j - NT2) * 64; }
        else          { Ab = A0; Bb = B0; kc = j * 64; }
    };

    // ---- prologue: A(0),B(0) -> slot0 ; A(1),B(1) -> slot1 (16 issues) ----
    {
        const ushort_t *Ab, *Bb; int kc;
        ABK(0, Ab, Bb, kc);
        STG(Ab, Ar0, kc, As[0], 0); STG(Ab, Ar0, kc, As[0], 1);
        STG(Bb, Br0, kc, Bs[0], 0); STG(Bb, Br0, kc, Bs[0], 1);
        ABK(1, Ab, Bb, kc);
        STG(Ab, Ar0, kc, As[1], 0); STG(Ab, Ar0, kc, As[1], 1);
        STG(Bb, Br0, kc, Bs[1], 0); STG(Bb, Br0, kc, Bs[1], 1);
    }
    asm volatile("s_waitcnt vmcnt(8)" ::: "memory");   // tile0's 8 retired (in-order)
    SBAR();

    auto ITER = [&](int t, f32x4 (&acc)[4][4]) {
        const int cur = t & 1;
        const ushort_t* Ac = As[cur];
        const ushort_t* Bc = Bs[t % 3];

        // stage B(t+2) early into Bs[(t+2)%3]: that buffer's readers finished at
        // iter t-1 (mid lgkm(0)+barrier), so the write overlaps this tile's compute
        if (t + 2 < NTT) {
            const ushort_t *A_2, *B_2; int kc2;
            ABK(t + 2, A_2, B_2, kc2);
            ushort_t* Bt = Bs[(t + 2) % 3];
            STG(B_2, Br0, kc2, Bt, 0); STG(B_2, Br0, kc2, Bt, 1);
        }

        // 16 frag reads; compiler interleaves MFMAs with fine-grained lgkmcnt
        #pragma unroll
        for (int mf = 0; mf < 4; ++mf) {
            a[mf][0] = FRAG(Ac, arow + mf * 16, 0);
            a[mf][1] = FRAG(Ac, arow + mf * 16, 64);
        }
        #pragma unroll
        for (int nf = 0; nf < 4; ++nf) {
            b[nf][0] = FRAG(Bc, brow + nf * 16, 0);
            b[nf][1] = FRAG(Bc, brow + nf * 16, 64);
        }
        __builtin_amdgcn_s_setprio(1);
        #pragma unroll
        for (int mf = 0; mf < 4; ++mf)
            #pragma unroll
            for (int nf = 0; nf < 4; ++nf) {
                acc[mf][nf] = MF(a[mf][0], b[nf][0], acc[mf][nf]);
                acc[mf][nf] = MF(a[mf][1], b[nf][1], acc[mf][nf]);
            }
        __builtin_amdgcn_s_setprio(0);
        // all reads of As[cur]/Bs[t%3] delivered (wave) -> barrier (block)
        asm volatile("s_waitcnt lgkmcnt(0)" ::: "memory");
        SCHED();
        SBAR();
        if (t + 2 < NTT) {
            const ushort_t *A_2, *B_2; int kc2;
            ABK(t + 2, A_2, B_2, kc2);
            STG(A_2, Ar0, kc2, As[cur], 0); STG(A_2, Ar0, kc2, As[cur], 1);
            // outstanding <= [B(t+2):4][A(t+2):4] after this wait -> t+1 landed
            asm volatile("s_waitcnt vmcnt(8)" ::: "memory");
        } else if (t + 1 < NTT) {
            asm volatile("s_waitcnt vmcnt(0)" ::: "memory");   // drain last prefetches
        }
        if (t + 1 < NTT) SBAR();
    };

    for (int t = 0; t < NT2; ++t)   ITER(t, accE);   // even-sample GEMM
    for (int t = NT2; t < NTT; ++t) ITER(t, accO);   // odd-sample GEMM

    // ---- combine + write: out(k) = accE+accO ; out(2048-k) = +-(accE-accO) ----
    // C/D layout: col = lane&15 (N side), row = (lane>>4)*4 + reg (M side)
    const int row_off = (lane >> 4) << 2;
    const int col_off = lane & 15;
    const int kg  = bm * 128 + wm * 64;
    const int ng0 = bn * 128 + wn * 64;

    #pragma unroll
    for (int nf = 0; nf < 4; ++nf) {
        const int ng = ng0 + nf * 16 + col_off;
        if (ng >= N_REAL) continue;
        const int s  = ng / NTIME;
        const int tt = ng - s * NTIME;
        const long rowbase = (long)s * NFREQ * NTIME;
        #pragma unroll
        for (int mf = 0; mf < 4; ++mf) {
            #pragma unroll
            for (int r = 0; r < 4; ++r) {
                const int k = kg + mf * 16 + row_off + r;
                if (k < MH) {
                    const float vE = accE[mf][nf][r];
                    const float vO = accO[mf][nf][r];
                    const float vP = vE + vO;
                    const float vM = g ? (vO - vE) : (vE - vO);
                    out[(rowbase + (long)k * NTIME + tt) * 2 + g]          = vP;
                    out[(rowbase + (long)(2048 - k) * NTIME + tt) * 2 + g] = vM;
                }
            }
        }
    }
}

extern "C" void kernel_launch(void* const* d_in, const int* in_sizes, int n_in,
                              void* d_out, int out_size, void* d_ws, size_t ws_size,
                              hipStream_t stream) {
    const float* x    = (const float*)d_in[0];
    float* out = (float*)d_out;

    ushort_t* Aall = (ushort_t*)d_ws;                     // 4 * 1152*1088*2B = 10.0MB
    ushort_t* Ball = Aall + 4L * M_PADH * KH;             // 4 * 3456*1088*2B = 30.1MB

    build_prep<<<2048, 256, 0, stream>>>(x, Aall, Ball);

    // 486 active blocks; pid encodes (chunk-index, g, XCD); grid padded to 496
    stft_gemm<<<496, 256, 0, stream>>>(Aall, Ball, out);
}